// Round 4
// baseline (79.880 us; speedup 1.0000x reference)
//
#include <hip/hip_runtime.h>
#include <math.h>

#define NN 16
#define GG 4096
#define STR 68            // LDS row stride (floats): item base banks spread (4i mod 32)
#define NWG GG            // 4096 blocks, 1 grid point per block

// compile-time reorder fence (HW: a wave's DS ops complete in order)
#define FENCE() asm volatile("" ::: "memory")

// Cooperative 8-thread in-place Gauss-Jordan inverse. Thread r holds row r in
// registers; pivot rows broadcast via __shfl within the 8-lane group (groups
// are lane-aligned: 8 | 64). On return row = row r of M^{-1}. Returns the
// pivot product (= det, same value on all 8 lanes). No pivoting: matrices
// are I + small perturbation or SPD.
__device__ __forceinline__ float gj_coop(float row[8], int r) {
    float pp = 1.0f;
#pragma unroll
    for (int k = 0; k < 8; ++k) {
        float Mk[8];
#pragma unroll
        for (int c = 0; c < 8; ++c) Mk[c] = __shfl(row[c], k, 8);
        float p = Mk[k];
        pp *= p;
        float ip = 1.0f / p;
        if (r == k) {
#pragma unroll
            for (int c = 0; c < 8; ++c) row[c] = Mk[c] * ip;
            row[k] = ip;
        } else {
            float dip = row[k] * ip;
#pragma unroll
            for (int c = 0; c < 8; ++c) row[c] = fmaf(-dip, Mk[c], row[c]);
            row[k] = -dip;
        }
    }
    return pp;
}

__global__ __launch_bounds__(256, 6) void pairkl_kernel(
    const float* __restrict__ omega, const float* __restrict__ links,
    const float* __restrict__ mu, const float* __restrict__ sigma,
    float* __restrict__ out) {
    __shared__ __align__(16) float sh_om[NN][STR];  // omega (stays)
    __shared__ __align__(16) float sh_sg[NN][STR];  // sigma -> Q (overlay by B-wave)
    __shared__ __align__(16) float sh_wv[NN][STR];  // V -> Winv (overlay by A-wave)
    __shared__ __align__(16) float sh_si[NN][STR];  // siginv -> P (overlay by A-wave)
    __shared__ float sh_mu[NN][9];
    __shared__ float sh_u [NN][9];                  // u_i = Winv mu
    __shared__ float sh_w [NN][9];                  // w_j = om^T si mu
    __shared__ float sh_sc[NN][4];                  // [0]=a_i  [1]=ld1->s_j  [2]=ldo
#define sh_P sh_si
#define sh_Q sh_sg

    const int bid = blockIdx.x;
    const int g   = (bid & 7) * (NWG / 8) + (bid >> 3);  // XCD-bijective swizzle
    const int t   = threadIdx.x;

    // ---- Phase 0: float4 staging; V = l0+l1-I straight into wv ----
    {
        const float4* om4 = (const float4*)omega;
        const float4* sg4 = (const float4*)sigma;
        const float4* lk4 = (const float4*)links;
        int q = t & 15, i = t >> 4;
        int b4 = (i * GG + g) * 16 + q;
        float4 o  = om4[b4];
        float4 s  = sg4[b4];
        float4 l0 = lk4[((i * 2 + 0) * GG + g) * 16 + q];
        float4 l1 = lk4[((i * 2 + 1) * GG + g) * 16 + q];
        float4 v  = make_float4(l0.x + l1.x, l0.y + l1.y, l0.z + l1.z, l0.w + l1.w);
        int e0 = q * 4;
        if (((e0 + 0) >> 3) == ((e0 + 0) & 7)) v.x -= 1.f;
        if (((e0 + 1) >> 3) == ((e0 + 1) & 7)) v.y -= 1.f;
        if (((e0 + 2) >> 3) == ((e0 + 2) & 7)) v.z -= 1.f;
        if (((e0 + 3) >> 3) == ((e0 + 3) & 7)) v.w -= 1.f;
        *(float4*)&sh_om[i][e0] = o;
        *(float4*)&sh_sg[i][e0] = s;
        *(float4*)&sh_wv[i][e0] = v;
        if (t < 128) sh_mu[t >> 3][t & 7] = mu[((t >> 3) * GG + g) * 8 + (t & 7)];
    }
    __syncthreads();

    float ldT_reg = 0.f;  // kept in-register across the barrier (A, r==0)

    // ---- Phase 1inv: A (t<128): T = om@V, Winv = T^{-1} -> wv, ldT.
    //                  B (t>=128): ldo = logdet(om); si = sg^{-1}, ld1. ----
    if (t < 128) {
        const int item = t >> 3, r = t & 7;
        const float* om = &sh_om[item][0];
        const float* vv = &sh_wv[item][0];
        float orow[8];
        *(float4*)&orow[0] = *(const float4*)&om[r * 8];
        *(float4*)&orow[4] = *(const float4*)&om[r * 8 + 4];
        float row[8] = {0, 0, 0, 0, 0, 0, 0, 0};
#pragma unroll
        for (int b = 0; b < 8; ++b) {
            const float4 v0 = *(const float4*)&vv[b * 8];
            const float4 v1 = *(const float4*)&vv[b * 8 + 4];
            float ob = orow[b];
            row[0] = fmaf(ob, v0.x, row[0]); row[1] = fmaf(ob, v0.y, row[1]);
            row[2] = fmaf(ob, v0.z, row[2]); row[3] = fmaf(ob, v0.w, row[3]);
            row[4] = fmaf(ob, v1.x, row[4]); row[5] = fmaf(ob, v1.y, row[5]);
            row[6] = fmaf(ob, v1.z, row[6]); row[7] = fmaf(ob, v1.w, row[7]);
        }
        float pp = gj_coop(row, r);  // row = Winv row r
        FENCE();  // all V reads (this wave) precede Winv writes; wave DS FIFO
        *(float4*)&sh_wv[item][r * 8]     = make_float4(row[0], row[1], row[2], row[3]);
        *(float4*)&sh_wv[item][r * 8 + 4] = make_float4(row[4], row[5], row[6], row[7]);
        ldT_reg = logf(fabsf(pp));
    } else {
        const int item = (t - 128) >> 3, r = t & 7;
        float row[8];
        *(float4*)&row[0] = *(const float4*)&sh_om[item][r * 8];
        *(float4*)&row[4] = *(const float4*)&sh_om[item][r * 8 + 4];
        float ppo = gj_coop(row, r);                 // det only, rows discarded
        *(float4*)&row[0] = *(const float4*)&sh_sg[item][r * 8];
        *(float4*)&row[4] = *(const float4*)&sh_sg[item][r * 8 + 4];
        float pps = gj_coop(row, r);                 // row = siginv row r
        *(float4*)&sh_si[item][r * 8]     = make_float4(row[0], row[1], row[2], row[3]);
        *(float4*)&sh_si[item][r * 8 + 4] = make_float4(row[4], row[5], row[6], row[7]);
        if (r == 0) {
            sh_sc[item][1] = logf(fabsf(pps));  // ld1
            sh_sc[item][2] = logf(fabsf(ppo));  // ldo
        }
    }
    __syncthreads();

    // ---- Phase 1b: A: P = om^T si om -> si, w, cc, final scalars.
    //                B: Q = wv sg wv^T -> sg, u = wv mu. ----
    if (t < 128) {
        const int item = t >> 3, r = t & 7;
        const float* om = &sh_om[item][0];
        const float* si = &sh_si[item][0];
        float mq[8];
#pragma unroll
        for (int b = 0; b < 8; ++b) mq[b] = sh_mu[item][b];
        float t1[8] = {0, 0, 0, 0, 0, 0, 0, 0};
#pragma unroll
        for (int a = 0; a < 8; ++a) {
            float oar = om[a * 8 + r];
            const float4 s0 = *(const float4*)&si[a * 8];
            const float4 s1 = *(const float4*)&si[a * 8 + 4];
            t1[0] = fmaf(oar, s0.x, t1[0]); t1[1] = fmaf(oar, s0.y, t1[1]);
            t1[2] = fmaf(oar, s0.z, t1[2]); t1[3] = fmaf(oar, s0.w, t1[3]);
            t1[4] = fmaf(oar, s1.x, t1[4]); t1[5] = fmaf(oar, s1.y, t1[5]);
            t1[6] = fmaf(oar, s1.z, t1[6]); t1[7] = fmaf(oar, s1.w, t1[7]);
        }
        float pr[8] = {0, 0, 0, 0, 0, 0, 0, 0};
#pragma unroll
        for (int b = 0; b < 8; ++b) {
            float tb = t1[b];
            const float4 o0 = *(const float4*)&om[b * 8];
            const float4 o1 = *(const float4*)&om[b * 8 + 4];
            pr[0] = fmaf(tb, o0.x, pr[0]); pr[1] = fmaf(tb, o0.y, pr[1]);
            pr[2] = fmaf(tb, o0.z, pr[2]); pr[3] = fmaf(tb, o0.w, pr[3]);
            pr[4] = fmaf(tb, o1.x, pr[4]); pr[5] = fmaf(tb, o1.y, pr[5]);
            pr[6] = fmaf(tb, o1.z, pr[6]); pr[7] = fmaf(tb, o1.w, pr[7]);
        }
        float ww = 0.f;
#pragma unroll
        for (int b = 0; b < 8; ++b) ww = fmaf(t1[b], mq[b], ww);
        float a_i = 0.f, s_i = 0.f;
        if (r == 0) {
            float cc = 0.f;
#pragma unroll
            for (int a = 0; a < 8; ++a) {
                float s = 0.f;
#pragma unroll
                for (int b = 0; b < 8; ++b) s = fmaf(si[a * 8 + b], mq[b], s);
                cc = fmaf(mq[a], s, cc);
            }
            float ld1 = sh_sc[item][1], ldo = sh_sc[item][2];
            a_i = 2.f * ldT_reg - ld1;
            s_i = ld1 - 2.f * ldo + cc - 8.0f;
        }
        FENCE();  // all si reads (this wave's items) precede P overlay writes
        *(float4*)&sh_P[item][r * 8]     = make_float4(pr[0], pr[1], pr[2], pr[3]);
        *(float4*)&sh_P[item][r * 8 + 4] = make_float4(pr[4], pr[5], pr[6], pr[7]);
        sh_w[item][r] = ww;
        if (r == 0) { sh_sc[item][0] = a_i; sh_sc[item][1] = s_i; }
    } else {
        const int item = (t - 128) >> 3, r = t & 7;
        const float* wv = &sh_wv[item][0];
        const float* sg = &sh_sg[item][0];
        float wrow[8];
        *(float4*)&wrow[0] = *(const float4*)&wv[r * 8];
        *(float4*)&wrow[4] = *(const float4*)&wv[r * 8 + 4];
        float mq[8];
#pragma unroll
        for (int b = 0; b < 8; ++b) mq[b] = sh_mu[item][b];
        float t2[8] = {0, 0, 0, 0, 0, 0, 0, 0};
#pragma unroll
        for (int b = 0; b < 8; ++b) {
            float wb = wrow[b];
            const float4 g0_ = *(const float4*)&sg[b * 8];
            const float4 g1_ = *(const float4*)&sg[b * 8 + 4];
            t2[0] = fmaf(wb, g0_.x, t2[0]); t2[1] = fmaf(wb, g0_.y, t2[1]);
            t2[2] = fmaf(wb, g0_.z, t2[2]); t2[3] = fmaf(wb, g0_.w, t2[3]);
            t2[4] = fmaf(wb, g1_.x, t2[4]); t2[5] = fmaf(wb, g1_.y, t2[5]);
            t2[6] = fmaf(wb, g1_.z, t2[6]); t2[7] = fmaf(wb, g1_.w, t2[7]);
        }
        float qr[8];
#pragma unroll
        for (int c = 0; c < 8; ++c) {
            const float4 w0 = *(const float4*)&wv[c * 8];
            const float4 w1 = *(const float4*)&wv[c * 8 + 4];
            float s = t2[0] * w0.x;
            s = fmaf(t2[1], w0.y, s); s = fmaf(t2[2], w0.z, s);
            s = fmaf(t2[3], w0.w, s); s = fmaf(t2[4], w1.x, s);
            s = fmaf(t2[5], w1.y, s); s = fmaf(t2[6], w1.z, s);
            s = fmaf(t2[7], w1.w, s);
            qr[c] = s;
        }
        float uu = wrow[0] * mq[0];
#pragma unroll
        for (int b = 1; b < 8; ++b) uu = fmaf(wrow[b], mq[b], uu);
        FENCE();  // all sg reads (this wave's items) precede Q overlay writes
        *(float4*)&sh_Q[item][r * 8]     = make_float4(qr[0], qr[1], qr[2], qr[3]);
        *(float4*)&sh_Q[item][r * 8 + 4] = make_float4(qr[4], qr[5], qr[6], qr[7]);
        sh_u[item][r] = uu;
    }
    __syncthreads();

    // ---- Phase 2: one (i,j) pair per thread ----
    const int i = t >> 4, j = t & 15;
    const float* Pj = &sh_P[j][0];
    const float* Qi = &sh_Q[i][0];
    float u[8];
#pragma unroll
    for (int b = 0; b < 8; ++b) u[b] = sh_u[i][b];
    float tr = 0.f, upu = 0.f;
#pragma unroll
    for (int a = 0; a < 8; ++a) {
        const float4 p0 = *(const float4*)&Pj[a * 8];
        const float4 p1 = *(const float4*)&Pj[a * 8 + 4];
        const float4 q0 = *(const float4*)&Qi[a * 8];
        const float4 q1 = *(const float4*)&Qi[a * 8 + 4];
        tr = fmaf(p0.x, q0.x, tr); tr = fmaf(p0.y, q0.y, tr);
        tr = fmaf(p0.z, q0.z, tr); tr = fmaf(p0.w, q0.w, tr);
        tr = fmaf(p1.x, q1.x, tr); tr = fmaf(p1.y, q1.y, tr);
        tr = fmaf(p1.z, q1.z, tr); tr = fmaf(p1.w, q1.w, tr);
        float s = p0.x * u[0];
        s = fmaf(p0.y, u[1], s); s = fmaf(p0.z, u[2], s);
        s = fmaf(p0.w, u[3], s); s = fmaf(p1.x, u[4], s);
        s = fmaf(p1.y, u[5], s); s = fmaf(p1.z, u[6], s);
        s = fmaf(p1.w, u[7], s);
        upu = fmaf(u[a], s, upu);
    }
    float wu = 0.f;
#pragma unroll
    for (int a = 0; a < 8; ++a) wu = fmaf(sh_w[j][a], u[a], wu);
    float E = 0.5f * (tr + upu - 2.f * wu + sh_sc[i][0] + sh_sc[j][1]);
    out[(i * NN + j) * GG + g] = (i == j) ? 0.0f : E;
}

extern "C" void kernel_launch(void* const* d_in, const int* in_sizes, int n_in,
                              void* d_out, int out_size, void* d_ws, size_t ws_size,
                              hipStream_t stream) {
    const float* omega = (const float*)d_in[0];
    const float* links = (const float*)d_in[1];
    const float* mu    = (const float*)d_in[2];
    const float* sigma = (const float*)d_in[3];
    float* out = (float*)d_out;
    hipLaunchKernelGGL(pairkl_kernel, dim3(NWG), dim3(256), 0, stream,
                       omega, links, mu, sigma, out);
}

// Round 5
// 38.774 us; speedup vs baseline: 2.0601x; 2.0601x over previous
//
#include <hip/hip_runtime.h>
#include <math.h>

#define NN 16
#define GG 4096
#define STR 68            // LDS row stride (floats): item base banks spread (4i mod 32)
#define NWG GG            // 4096 blocks, 1 grid point per block

// Cooperative 8-thread in-place Gauss-Jordan inverse. Thread r holds row r in
// registers; pivot rows broadcast via __shfl within the 8-lane group (groups
// are lane-aligned: 8 | 64). On return row = row r of M^{-1}. Returns the
// pivot product (= det, same value on all 8 lanes). No pivoting: matrices
// are I + small perturbation or SPD.
__device__ __forceinline__ float gj_coop(float row[8], int r) {
    float pp = 1.0f;
#pragma unroll
    for (int k = 0; k < 8; ++k) {
        float Mk[8];
#pragma unroll
        for (int c = 0; c < 8; ++c) Mk[c] = __shfl(row[c], k, 8);
        float p = Mk[k];
        pp *= p;
        float ip = 1.0f / p;
        if (r == k) {
#pragma unroll
            for (int c = 0; c < 8; ++c) row[c] = Mk[c] * ip;
            row[k] = ip;
        } else {
            float dip = row[k] * ip;
#pragma unroll
            for (int c = 0; c < 8; ++c) row[c] = fmaf(-dip, Mk[c], row[c]);
            row[k] = -dip;
        }
    }
    return pp;
}

__global__ __launch_bounds__(256) void pairkl_kernel(
    const float* __restrict__ omega, const float* __restrict__ links,
    const float* __restrict__ mu, const float* __restrict__ sigma,
    float* __restrict__ out) {
    __shared__ __align__(16) float sh_om[NN][STR];  // omega (never overwritten)
    __shared__ __align__(16) float sh_sg[NN][STR];  // sigma -> Q (overlay by B-half)
    __shared__ __align__(16) float sh_wv[NN][STR];  // V -> Winv (overlay by A-half)
    __shared__ __align__(16) float sh_si[NN][STR];  // siginv -> P (overlay by A-half)
    __shared__ float sh_mu[NN][9];
    __shared__ float sh_u [NN][9];                  // u_i = Winv mu
    __shared__ float sh_w [NN][9];                  // w_j = om^T si mu
    __shared__ float sh_sc[NN][4];                  // [0]=a_i  [1]=ld1->s_j  [2]=ldo
#define sh_P sh_si
#define sh_Q sh_sg

    const int bid = blockIdx.x;
    const int g   = (bid & 7) * (NWG / 8) + (bid >> 3);  // XCD-bijective swizzle
    const int t   = threadIdx.x;

    // ---- Phase 0: float4 staging; V = l0+l1-I straight into wv ----
    {
        const float4* om4 = (const float4*)omega;
        const float4* sg4 = (const float4*)sigma;
        const float4* lk4 = (const float4*)links;
        int q = t & 15, i = t >> 4;
        int b4 = (i * GG + g) * 16 + q;
        float4 o  = om4[b4];
        float4 s  = sg4[b4];
        float4 l0 = lk4[((i * 2 + 0) * GG + g) * 16 + q];
        float4 l1 = lk4[((i * 2 + 1) * GG + g) * 16 + q];
        float4 v  = make_float4(l0.x + l1.x, l0.y + l1.y, l0.z + l1.z, l0.w + l1.w);
        int e0 = q * 4;
        if (((e0 + 0) >> 3) == ((e0 + 0) & 7)) v.x -= 1.f;
        if (((e0 + 1) >> 3) == ((e0 + 1) & 7)) v.y -= 1.f;
        if (((e0 + 2) >> 3) == ((e0 + 2) & 7)) v.z -= 1.f;
        if (((e0 + 3) >> 3) == ((e0 + 3) & 7)) v.w -= 1.f;
        *(float4*)&sh_om[i][e0] = o;
        *(float4*)&sh_sg[i][e0] = s;
        *(float4*)&sh_wv[i][e0] = v;
        if (t < 128) sh_mu[t >> 3][t & 7] = mu[((t >> 3) * GG + g) * 8 + (t & 7)];
    }
    __syncthreads();

    float ldT_reg = 0.f;  // kept in-register across the barrier (A-half)

    // ---- Phase 1inv: A (t<128): T = om@V, Winv = T^{-1} -> wv, ldT.
    //                  B (t>=128): ldo = logdet(om); si = sg^{-1}, ld1. ----
    if (t < 128) {
        const int item = t >> 3, r = t & 7;
        const float* om = &sh_om[item][0];
        const float* vv = &sh_wv[item][0];
        float orow[8];
        *(float4*)&orow[0] = *(const float4*)&om[r * 8];
        *(float4*)&orow[4] = *(const float4*)&om[r * 8 + 4];
        float row[8] = {0, 0, 0, 0, 0, 0, 0, 0};
#pragma unroll
        for (int b = 0; b < 8; ++b) {
            const float4 v0 = *(const float4*)&vv[b * 8];
            const float4 v1 = *(const float4*)&vv[b * 8 + 4];
            float ob = orow[b];
            row[0] = fmaf(ob, v0.x, row[0]); row[1] = fmaf(ob, v0.y, row[1]);
            row[2] = fmaf(ob, v0.z, row[2]); row[3] = fmaf(ob, v0.w, row[3]);
            row[4] = fmaf(ob, v1.x, row[4]); row[5] = fmaf(ob, v1.y, row[5]);
            row[6] = fmaf(ob, v1.z, row[6]); row[7] = fmaf(ob, v1.w, row[7]);
        }
        float pp = gj_coop(row, r);  // row = Winv row r
        // store after reads of same buffer: per-thread alias keeps order,
        // wave lockstep makes it safe across the 8-lane group.
        *(float4*)&sh_wv[item][r * 8]     = make_float4(row[0], row[1], row[2], row[3]);
        *(float4*)&sh_wv[item][r * 8 + 4] = make_float4(row[4], row[5], row[6], row[7]);
        ldT_reg = logf(fabsf(pp));
    } else {
        const int item = (t - 128) >> 3, r = t & 7;
        float row[8];
        *(float4*)&row[0] = *(const float4*)&sh_om[item][r * 8];
        *(float4*)&row[4] = *(const float4*)&sh_om[item][r * 8 + 4];
        float ppo = gj_coop(row, r);                 // det only, rows discarded
        *(float4*)&row[0] = *(const float4*)&sh_sg[item][r * 8];
        *(float4*)&row[4] = *(const float4*)&sh_sg[item][r * 8 + 4];
        float pps = gj_coop(row, r);                 // row = siginv row r
        *(float4*)&sh_si[item][r * 8]     = make_float4(row[0], row[1], row[2], row[3]);
        *(float4*)&sh_si[item][r * 8 + 4] = make_float4(row[4], row[5], row[6], row[7]);
        if (r == 0) {
            sh_sc[item][1] = logf(fabsf(pps));  // ld1
            sh_sc[item][2] = logf(fabsf(ppo));  // ldo
        }
    }
    __syncthreads();

    // ---- Phase 1b: A: P = om^T si om -> si, w, cc, final scalars.
    //                B: Q = wv sg wv^T -> sg, u = wv mu. ----
    if (t < 128) {
        const int item = t >> 3, r = t & 7;
        const float* om = &sh_om[item][0];
        const float* si = &sh_si[item][0];
        float mq[8];
#pragma unroll
        for (int b = 0; b < 8; ++b) mq[b] = sh_mu[item][b];
        // t1 = row r of (om^T si)
        float t1[8] = {0, 0, 0, 0, 0, 0, 0, 0};
#pragma unroll
        for (int a = 0; a < 8; ++a) {
            float oar = om[a * 8 + r];
            const float4 s0 = *(const float4*)&si[a * 8];
            const float4 s1 = *(const float4*)&si[a * 8 + 4];
            t1[0] = fmaf(oar, s0.x, t1[0]); t1[1] = fmaf(oar, s0.y, t1[1]);
            t1[2] = fmaf(oar, s0.z, t1[2]); t1[3] = fmaf(oar, s0.w, t1[3]);
            t1[4] = fmaf(oar, s1.x, t1[4]); t1[5] = fmaf(oar, s1.y, t1[5]);
            t1[6] = fmaf(oar, s1.z, t1[6]); t1[7] = fmaf(oar, s1.w, t1[7]);
        }
        // prow = t1 @ om
        float pr[8] = {0, 0, 0, 0, 0, 0, 0, 0};
#pragma unroll
        for (int b = 0; b < 8; ++b) {
            float tb = t1[b];
            const float4 o0 = *(const float4*)&om[b * 8];
            const float4 o1 = *(const float4*)&om[b * 8 + 4];
            pr[0] = fmaf(tb, o0.x, pr[0]); pr[1] = fmaf(tb, o0.y, pr[1]);
            pr[2] = fmaf(tb, o0.z, pr[2]); pr[3] = fmaf(tb, o0.w, pr[3]);
            pr[4] = fmaf(tb, o1.x, pr[4]); pr[5] = fmaf(tb, o1.y, pr[5]);
            pr[6] = fmaf(tb, o1.z, pr[6]); pr[7] = fmaf(tb, o1.w, pr[7]);
        }
        float ww = 0.f;
#pragma unroll
        for (int b = 0; b < 8; ++b) ww = fmaf(t1[b], mq[b], ww);
        // cc = mu^T si mu, parallel over the 8-lane group
        float part;
        {
            const float4 s0 = *(const float4*)&si[r * 8];
            const float4 s1 = *(const float4*)&si[r * 8 + 4];
            float sr = s0.x * mq[0];
            sr = fmaf(s0.y, mq[1], sr); sr = fmaf(s0.z, mq[2], sr);
            sr = fmaf(s0.w, mq[3], sr); sr = fmaf(s1.x, mq[4], sr);
            sr = fmaf(s1.y, mq[5], sr); sr = fmaf(s1.z, mq[6], sr);
            sr = fmaf(s1.w, mq[7], sr);
            part = mq[r] * sr;
        }
        part += __shfl_xor(part, 1, 8);
        part += __shfl_xor(part, 2, 8);
        part += __shfl_xor(part, 4, 8);
        float a_i = 0.f, s_i = 0.f;
        if (r == 0) {
            float ld1 = sh_sc[item][1], ldo = sh_sc[item][2];
            a_i = 2.f * ldT_reg - ld1;
            s_i = ld1 - 2.f * ldo + part - 8.0f;
        }
        *(float4*)&sh_P[item][r * 8]     = make_float4(pr[0], pr[1], pr[2], pr[3]);
        *(float4*)&sh_P[item][r * 8 + 4] = make_float4(pr[4], pr[5], pr[6], pr[7]);
        sh_w[item][r] = ww;
        if (r == 0) { sh_sc[item][0] = a_i; sh_sc[item][1] = s_i; }
    } else {
        const int item = (t - 128) >> 3, r = t & 7;
        const float* wv = &sh_wv[item][0];
        const float* sg = &sh_sg[item][0];
        float wrow[8];
        *(float4*)&wrow[0] = *(const float4*)&wv[r * 8];
        *(float4*)&wrow[4] = *(const float4*)&wv[r * 8 + 4];
        float mq[8];
#pragma unroll
        for (int b = 0; b < 8; ++b) mq[b] = sh_mu[item][b];
        float t2[8] = {0, 0, 0, 0, 0, 0, 0, 0};
#pragma unroll
        for (int b = 0; b < 8; ++b) {
            float wb = wrow[b];
            const float4 g0_ = *(const float4*)&sg[b * 8];
            const float4 g1_ = *(const float4*)&sg[b * 8 + 4];
            t2[0] = fmaf(wb, g0_.x, t2[0]); t2[1] = fmaf(wb, g0_.y, t2[1]);
            t2[2] = fmaf(wb, g0_.z, t2[2]); t2[3] = fmaf(wb, g0_.w, t2[3]);
            t2[4] = fmaf(wb, g1_.x, t2[4]); t2[5] = fmaf(wb, g1_.y, t2[5]);
            t2[6] = fmaf(wb, g1_.z, t2[6]); t2[7] = fmaf(wb, g1_.w, t2[7]);
        }
        float qr[8];
#pragma unroll
        for (int c = 0; c < 8; ++c) {
            const float4 w0 = *(const float4*)&wv[c * 8];
            const float4 w1 = *(const float4*)&wv[c * 8 + 4];
            float s = t2[0] * w0.x;
            s = fmaf(t2[1], w0.y, s); s = fmaf(t2[2], w0.z, s);
            s = fmaf(t2[3], w0.w, s); s = fmaf(t2[4], w1.x, s);
            s = fmaf(t2[5], w1.y, s); s = fmaf(t2[6], w1.z, s);
            s = fmaf(t2[7], w1.w, s);
            qr[c] = s;
        }
        float uu = wrow[0] * mq[0];
#pragma unroll
        for (int b = 1; b < 8; ++b) uu = fmaf(wrow[b], mq[b], uu);
        *(float4*)&sh_Q[item][r * 8]     = make_float4(qr[0], qr[1], qr[2], qr[3]);
        *(float4*)&sh_Q[item][r * 8 + 4] = make_float4(qr[4], qr[5], qr[6], qr[7]);
        sh_u[item][r] = uu;
    }
    __syncthreads();

    // ---- Phase 2: one (i,j) pair per thread ----
    const int i = t >> 4, j = t & 15;
    const float* Pj = &sh_P[j][0];
    const float* Qi = &sh_Q[i][0];
    float u[8];
#pragma unroll
    for (int b = 0; b < 8; ++b) u[b] = sh_u[i][b];
    float tr = 0.f, upu = 0.f;
#pragma unroll
    for (int a = 0; a < 8; ++a) {
        const float4 p0 = *(const float4*)&Pj[a * 8];
        const float4 p1 = *(const float4*)&Pj[a * 8 + 4];
        const float4 q0 = *(const float4*)&Qi[a * 8];
        const float4 q1 = *(const float4*)&Qi[a * 8 + 4];
        tr = fmaf(p0.x, q0.x, tr); tr = fmaf(p0.y, q0.y, tr);
        tr = fmaf(p0.z, q0.z, tr); tr = fmaf(p0.w, q0.w, tr);
        tr = fmaf(p1.x, q1.x, tr); tr = fmaf(p1.y, q1.y, tr);
        tr = fmaf(p1.z, q1.z, tr); tr = fmaf(p1.w, q1.w, tr);
        float s = p0.x * u[0];
        s = fmaf(p0.y, u[1], s); s = fmaf(p0.z, u[2], s);
        s = fmaf(p0.w, u[3], s); s = fmaf(p1.x, u[4], s);
        s = fmaf(p1.y, u[5], s); s = fmaf(p1.z, u[6], s);
        s = fmaf(p1.w, u[7], s);
        upu = fmaf(u[a], s, upu);
    }
    float wu = 0.f;
#pragma unroll
    for (int a = 0; a < 8; ++a) wu = fmaf(sh_w[j][a], u[a], wu);
    float E = 0.5f * (tr + upu - 2.f * wu + sh_sc[i][0] + sh_sc[j][1]);
    out[(i * NN + j) * GG + g] = (i == j) ? 0.0f : E;
}

extern "C" void kernel_launch(void* const* d_in, const int* in_sizes, int n_in,
                              void* d_out, int out_size, void* d_ws, size_t ws_size,
                              hipStream_t stream) {
    const float* omega = (const float*)d_in[0];
    const float* links = (const float*)d_in[1];
    const float* mu    = (const float*)d_in[2];
    const float* sigma = (const float*)d_in[3];
    float* out = (float*)d_out;
    hipLaunchKernelGGL(pairkl_kernel, dim3(NWG), dim3(256), 0, stream,
                       omega, links, mu, sigma, out);
}

// Round 6
// 29.665 us; speedup vs baseline: 2.6927x; 1.3071x over previous
//
#include <hip/hip_runtime.h>
#include <math.h>

#define NN 16
#define GG 4096
#define GP 2
#define STR 68            // LDS row stride (floats): item bases spread 4i mod 32 banks
#define NWG (GG / GP)     // 2048 blocks

// ---- DPP helpers (quad_perm = VALU cross-lane, no DS pipe) ----
template <int CTRL>
__device__ __forceinline__ float dppf(float x) {
    return __builtin_bit_cast(float, __builtin_amdgcn_mov_dpp(
        __builtin_bit_cast(int, x), CTRL, 0xF, 0xF, true));
}
// broadcast lane L (0..3) of each quad
__device__ __forceinline__ float qb(float x, int L) {
    switch (L) {
        case 0:  return dppf<0x00>(x);
        case 1:  return dppf<0x55>(x);
        case 2:  return dppf<0xAA>(x);
        default: return dppf<0xFF>(x);
    }
}
// sum over the 4 lanes of a quad (butterflies via quad_perm)
__device__ __forceinline__ float qsum(float x) {
    x += dppf<0xB1>(x);  // perm[1,0,3,2]
    x += dppf<0x4E>(x);  // perm[2,3,0,1]
    return x;
}
// broadcast row k (rows {q,q+4} live in lanes' r0/r1) to all 4 lanes
__device__ __forceinline__ void bcast_row(float out[8], const float r0[8],
                                          const float r1[8], int k) {
#pragma unroll
    for (int c = 0; c < 8; ++c) {
        float s = (k < 4) ? r0[c] : r1[c];
        out[c] = qb(s, k & 3);
    }
}
__device__ __forceinline__ float sel_lo(const float r[8], int q) {
    return (q == 0) ? r[0] : (q == 1) ? r[1] : (q == 2) ? r[2] : r[3];
}
__device__ __forceinline__ float sel_hi(const float r[8], int q) {
    return (q == 0) ? r[4] : (q == 1) ? r[5] : (q == 2) ? r[6] : r[7];
}
__device__ __forceinline__ void ld_row(float r[8], const float* p) {
    float4 x = *(const float4*)p, y = *(const float4*)(p + 4);
    r[0] = x.x; r[1] = x.y; r[2] = x.z; r[3] = x.w;
    r[4] = y.x; r[5] = y.y; r[6] = y.z; r[7] = y.w;
}
__device__ __forceinline__ void st_row(float* p, const float r[8]) {
    *(float4*)p       = make_float4(r[0], r[1], r[2], r[3]);
    *(float4*)(p + 4) = make_float4(r[4], r[5], r[6], r[7]);
}
__device__ __forceinline__ float dot8(const float a[8], const float b[8]) {
    float s = a[0] * b[0];
    s = fmaf(a[1], b[1], s); s = fmaf(a[2], b[2], s);
    s = fmaf(a[3], b[3], s); s = fmaf(a[4], b[4], s);
    s = fmaf(a[5], b[5], s); s = fmaf(a[6], b[6], s);
    s = fmaf(a[7], b[7], s);
    return s;
}

// 4-lane cooperative Gauss-Jordan: lane q holds rows q (r0) and q+4 (r1).
// On return rows hold M^{-1}. Returns pivot product (det), same on all lanes.
// No pivoting (matrices are I+eps or SPD).
__device__ __forceinline__ float gj4(float r0[8], float r1[8], int q) {
    float pp = 1.0f;
#pragma unroll
    for (int k = 0; k < 8; ++k) {
        float Mk[8];
        bcast_row(Mk, r0, r1, k);
        float p = Mk[k];
        pp *= p;
        float ip = 1.0f / p;
        bool own0 = (k < 4) && (q == k);
        bool own1 = (k >= 4) && (q == k - 4);
        float m0 = -(own0 ? -1.0f : r0[k]) * ip;
        float m1 = -(own1 ? -1.0f : r1[k]) * ip;
#pragma unroll
        for (int c = 0; c < 8; ++c) {
            float b0 = own0 ? 0.0f : r0[c];
            float b1 = own1 ? 0.0f : r1[c];
            r0[c] = fmaf(m0, Mk[c], b0);
            r1[c] = fmaf(m1, Mk[c], b1);
        }
        r0[k] = m0;
        r1[k] = m1;
    }
    return pp;
}

__global__ __launch_bounds__(256) void pairkl_kernel(
    const float* __restrict__ omega, const float* __restrict__ links,
    const float* __restrict__ mu, const float* __restrict__ sigma,
    float* __restrict__ out) {
    __shared__ __align__(16) float sh_om[GP][NN][STR];  // omega -> P (B-wave overlay)
    __shared__ __align__(16) float sh_sg[GP][NN][STR];  // sigma (persists)
    __shared__ __align__(16) float sh_wv[GP][NN][STR];  // V -> Q (A-wave overlay)
    __shared__ __align__(16) float sh_mu[GP][NN][8];
    __shared__ __align__(16) float sh_u [GP][NN][8];
    __shared__ __align__(16) float sh_w [GP][NN][8];
    __shared__ __align__(16) float sh_sc[GP][NN][4];    // [2ldT, 2ldo, ld1, cc]

    const int bid  = blockIdx.x;
    const int work = (bid & 7) * (NWG / 8) + (bid >> 3);  // XCD-bijective swizzle
    const int g0   = work * GP;
    const int t    = threadIdx.x;

    // ---- Phase 0: float4 staging; V = l0+l1-I into wv ----
    {
        const int gl = t >> 7, s = t & 127;
        const int g  = g0 + gl;
        const float4* om4 = (const float4*)omega;
        const float4* sg4 = (const float4*)sigma;
        const float4* lk4 = (const float4*)links;
#pragma unroll
        for (int k = 0; k < 2; ++k) {
            int fc = s + 128 * k;
            int i = fc >> 4, qq = fc & 15;
            int b4 = (i * GG + g) * 16 + qq;
            float4 o  = om4[b4];
            float4 sv = sg4[b4];
            float4 l0 = lk4[((i * 2 + 0) * GG + g) * 16 + qq];
            float4 l1 = lk4[((i * 2 + 1) * GG + g) * 16 + qq];
            float4 v = make_float4(l0.x + l1.x, l0.y + l1.y, l0.z + l1.z, l0.w + l1.w);
            int e0 = qq * 4;
            if (((e0 + 0) >> 3) == ((e0 + 0) & 7)) v.x -= 1.f;
            if (((e0 + 1) >> 3) == ((e0 + 1) & 7)) v.y -= 1.f;
            if (((e0 + 2) >> 3) == ((e0 + 2) & 7)) v.z -= 1.f;
            if (((e0 + 3) >> 3) == ((e0 + 3) & 7)) v.w -= 1.f;
            *(float4*)&sh_om[gl][i][e0] = o;
            *(float4*)&sh_sg[gl][i][e0] = sv;
            *(float4*)&sh_wv[gl][i][e0] = v;
        }
        if (t < 64) {
            int gl2 = t >> 5, mi = (t >> 1) & 15, h = t & 1;
            const float4* mu4 = (const float4*)mu;
            *(float4*)&sh_mu[gl2][mi][h * 4] = mu4[(mi * GG + g0 + gl2) * 2 + h];
        }
    }
    __syncthreads();

    // wave roles: w0: A(g0), w1: A(g1), w2: B(g0), w3: B(g1)
    const int wid  = t >> 6;
    const int gl   = wid & 1;
    const int isB  = wid >> 1;
    const int lane = t & 63;
    const int item = lane >> 2;
    const int q    = lane & 3;

    float R0[8], R1[8];  // A: Winv rows {q,q+4};  B: siginv rows {q,q+4}
    float mq[8];
    ld_row(mq, &sh_mu[gl][item][0]);

    // ---- Phase 1a ----
    if (!isB) {
        // T = omega @ V (rows q,q+4), then Winv = T^{-1}
        float o0[8], o1[8];
        ld_row(o0, &sh_om[gl][item][q * 8]);
        ld_row(o1, &sh_om[gl][item][(q + 4) * 8]);
#pragma unroll
        for (int c = 0; c < 8; ++c) { R0[c] = 0.f; R1[c] = 0.f; }
        const float* vv = &sh_wv[gl][item][0];
#pragma unroll
        for (int b = 0; b < 8; ++b) {
            float vr[8]; ld_row(vr, vv + b * 8);
#pragma unroll
            for (int c = 0; c < 8; ++c) {
                R0[c] = fmaf(o0[b], vr[c], R0[c]);
                R1[c] = fmaf(o1[b], vr[c], R1[c]);
            }
        }
        float ppT = gj4(R0, R1, q);
        if (q == 0) sh_sc[gl][item][0] = 2.0f * logf(fabsf(ppT));
    } else {
        // det(omega); siginv = sigma^{-1}; cc = mu^T siginv mu
        float a0[8], a1[8];
        ld_row(a0, &sh_om[gl][item][q * 8]);
        ld_row(a1, &sh_om[gl][item][(q + 4) * 8]);
        float ppo = gj4(a0, a1, q);  // inverse discarded
        ld_row(R0, &sh_sg[gl][item][q * 8]);
        ld_row(R1, &sh_sg[gl][item][(q + 4) * 8]);
        float pps = gj4(R0, R1, q);
        float cq = dot8(R0, mq) * sel_lo(mq, q) + dot8(R1, mq) * sel_hi(mq, q);
        float cc = qsum(cq);
        if (q == 0) {
            sh_sc[gl][item][1] = 2.0f * logf(fabsf(ppo));
            sh_sc[gl][item][2] = logf(fabsf(pps));
            sh_sc[gl][item][3] = cc;
        }
    }
    __syncthreads();

    // ---- Phase 1b ----
    if (!isB) {
        // Z = Winv sigma ; Q = Z Winv^T -> sh_wv ; u = Winv mu
        float Z0[8], Z1[8];
#pragma unroll
        for (int c = 0; c < 8; ++c) { Z0[c] = 0.f; Z1[c] = 0.f; }
        const float* sg = &sh_sg[gl][item][0];
#pragma unroll
        for (int b = 0; b < 8; ++b) {
            float sr[8]; ld_row(sr, sg + b * 8);
#pragma unroll
            for (int c = 0; c < 8; ++c) {
                Z0[c] = fmaf(R0[b], sr[c], Z0[c]);
                Z1[c] = fmaf(R1[b], sr[c], Z1[c]);
            }
        }
        float Q0[8], Q1[8];
#pragma unroll
        for (int c = 0; c < 8; ++c) {
            float Wc[8]; bcast_row(Wc, R0, R1, c);
            Q0[c] = dot8(Z0, Wc);
            Q1[c] = dot8(Z1, Wc);
        }
        st_row(&sh_wv[gl][item][q * 8], Q0);        // V dead (read fully in 1a)
        st_row(&sh_wv[gl][item][(q + 4) * 8], Q1);
        sh_u[gl][item][q]     = dot8(R0, mq);
        sh_u[gl][item][q + 4] = dot8(R1, mq);
    } else {
        // S = siginv omega ; P = omega^T S -> sh_om ; w = S^T mu
        float S0[8], S1[8], oq[8], oq4[8];
#pragma unroll
        for (int c = 0; c < 8; ++c) { S0[c] = 0.f; S1[c] = 0.f; }
        const float* om = &sh_om[gl][item][0];
#pragma unroll
        for (int b = 0; b < 8; ++b) {
            float orow[8]; ld_row(orow, om + b * 8);
#pragma unroll
            for (int c = 0; c < 8; ++c) {
                S0[c] = fmaf(R0[b], orow[c], S0[c]);
                S1[c] = fmaf(R1[b], orow[c], S1[c]);
            }
            oq[b]  = sel_lo(orow, q);   // omega[b][q]
            oq4[b] = sel_hi(orow, q);   // omega[b][q+4]
        }
        float P0[8], P1[8];
#pragma unroll
        for (int c = 0; c < 8; ++c) { P0[c] = 0.f; P1[c] = 0.f; }
#pragma unroll
        for (int a = 0; a < 8; ++a) {
            float Sa[8]; bcast_row(Sa, S0, S1, a);
#pragma unroll
            for (int c = 0; c < 8; ++c) {
                P0[c] = fmaf(oq[a],  Sa[c], P0[c]);
                P1[c] = fmaf(oq4[a], Sa[c], P1[c]);
            }
        }
        float wp[8];
        {
            float mlo = sel_lo(mq, q), mhi = sel_hi(mq, q);
#pragma unroll
            for (int c = 0; c < 8; ++c)
                wp[c] = qsum(fmaf(mlo, S0[c], mhi * S1[c]));
        }
        st_row(&sh_om[gl][item][q * 8], P0);        // om dead (own reads precede)
        st_row(&sh_om[gl][item][(q + 4) * 8], P1);
        if (q == 0) st_row(&sh_w[gl][item][0], wp);
    }
    __syncthreads();

    // ---- Phase 2: thread -> (gl, i, {j, j+8}) ----
    {
        const int gl2 = t >> 7, r2 = t & 127;
        const int i2 = r2 >> 3, jb = r2 & 7;
        const int j0 = jb, j1 = jb + 8;
        const float* Qp = &sh_wv[gl2][i2][0];
        const float* Pa = &sh_om[gl2][j0][0];
        const float* Pb = &sh_om[gl2][j1][0];
        float u[8]; ld_row(u, &sh_u[gl2][i2][0]);
        float tr0 = 0.f, tr1 = 0.f, up0 = 0.f, up1 = 0.f;
#pragma unroll
        for (int a = 0; a < 8; ++a) {
            float qr[8]; ld_row(qr, Qp + a * 8);
            float p0[8]; ld_row(p0, Pa + a * 8);
            float p1[8]; ld_row(p1, Pb + a * 8);
            float s0 = 0.f, s1 = 0.f;
#pragma unroll
            for (int c = 0; c < 8; ++c) {
                tr0 = fmaf(p0[c], qr[c], tr0);
                tr1 = fmaf(p1[c], qr[c], tr1);
                s0  = fmaf(p0[c], u[c], s0);
                s1  = fmaf(p1[c], u[c], s1);
            }
            up0 = fmaf(u[a], s0, up0);
            up1 = fmaf(u[a], s1, up1);
        }
        float w0[8]; ld_row(w0, &sh_w[gl2][j0][0]);
        float w1[8]; ld_row(w1, &sh_w[gl2][j1][0]);
        float wu0 = dot8(w0, u), wu1 = dot8(w1, u);
        float4 sci = *(const float4*)&sh_sc[gl2][i2][0];
        float4 sj0 = *(const float4*)&sh_sc[gl2][j0][0];
        float4 sj1 = *(const float4*)&sh_sc[gl2][j1][0];
        float ai  = sci.x - sci.z;                       // 2ldT_i - ld1_i
        float s0j = sj0.z - sj0.y + sj0.w - 8.0f;        // ld1_j - 2ldo_j + cc_j - 8
        float s1j = sj1.z - sj1.y + sj1.w - 8.0f;
        float E0 = 0.5f * (tr0 + up0 - 2.f * wu0 + ai + s0j);
        float E1 = 0.5f * (tr1 + up1 - 2.f * wu1 + ai + s1j);
        int g = g0 + gl2;
        out[(i2 * NN + j0) * GG + g] = (i2 == j0) ? 0.f : E0;
        out[(i2 * NN + j1) * GG + g] = (i2 == j1) ? 0.f : E1;
    }
}

extern "C" void kernel_launch(void* const* d_in, const int* in_sizes, int n_in,
                              void* d_out, int out_size, void* d_ws, size_t ws_size,
                              hipStream_t stream) {
    const float* omega = (const float*)d_in[0];
    const float* links = (const float*)d_in[1];
    const float* mu    = (const float*)d_in[2];
    const float* sigma = (const float*)d_in[3];
    float* out = (float*)d_out;
    hipLaunchKernelGGL(pairkl_kernel, dim3(NWG), dim3(256), 0, stream,
                       omega, links, mu, sigma, out);
}

// Round 7
// 29.526 us; speedup vs baseline: 2.7054x; 1.0047x over previous
//
#include <hip/hip_runtime.h>
#include <math.h>

#define NN 16
#define GG 4096
#define GP 2
#define STR 76            // stride (floats): 76 mod 32 = 12 -> 8 distinct banks over i/j
#define NWG (GG / GP)     // 2048 blocks

// ---- DPP helpers (quad_perm = VALU cross-lane, no DS pipe) ----
template <int CTRL>
__device__ __forceinline__ float dppf(float x) {
    return __builtin_bit_cast(float, __builtin_amdgcn_mov_dpp(
        __builtin_bit_cast(int, x), CTRL, 0xF, 0xF, true));
}
__device__ __forceinline__ float qb(float x, int L) {
    switch (L) {
        case 0:  return dppf<0x00>(x);
        case 1:  return dppf<0x55>(x);
        case 2:  return dppf<0xAA>(x);
        default: return dppf<0xFF>(x);
    }
}
__device__ __forceinline__ float qsum(float x) {
    x += dppf<0xB1>(x);  // perm[1,0,3,2]
    x += dppf<0x4E>(x);  // perm[2,3,0,1]
    return x;
}
__device__ __forceinline__ void bcast_row(float out[8], const float r0[8],
                                          const float r1[8], int k) {
#pragma unroll
    for (int c = 0; c < 8; ++c) {
        float s = (k < 4) ? r0[c] : r1[c];
        out[c] = qb(s, k & 3);
    }
}
__device__ __forceinline__ float sel_lo(const float r[8], int q) {
    return (q == 0) ? r[0] : (q == 1) ? r[1] : (q == 2) ? r[2] : r[3];
}
__device__ __forceinline__ float sel_hi(const float r[8], int q) {
    return (q == 0) ? r[4] : (q == 1) ? r[5] : (q == 2) ? r[6] : r[7];
}
__device__ __forceinline__ void ld_row(float r[8], const float* p) {
    float4 x = *(const float4*)p, y = *(const float4*)(p + 4);
    r[0] = x.x; r[1] = x.y; r[2] = x.z; r[3] = x.w;
    r[4] = y.x; r[5] = y.y; r[6] = y.z; r[7] = y.w;
}
__device__ __forceinline__ void st_row(float* p, const float r[8]) {
    *(float4*)p       = make_float4(r[0], r[1], r[2], r[3]);
    *(float4*)(p + 4) = make_float4(r[4], r[5], r[6], r[7]);
}
__device__ __forceinline__ float dot8(const float a[8], const float b[8]) {
    float s = a[0] * b[0];
    s = fmaf(a[1], b[1], s); s = fmaf(a[2], b[2], s);
    s = fmaf(a[3], b[3], s); s = fmaf(a[4], b[4], s);
    s = fmaf(a[5], b[5], s); s = fmaf(a[6], b[6], s);
    s = fmaf(a[7], b[7], s);
    return s;
}

// 4-lane cooperative Gauss-Jordan: lane q holds rows q (r0) and q+4 (r1).
// On return rows hold M^{-1}. Returns pivot product (det), same on all lanes.
__device__ __forceinline__ float gj4(float r0[8], float r1[8], int q) {
    float pp = 1.0f;
#pragma unroll
    for (int k = 0; k < 8; ++k) {
        float Mk[8];
        bcast_row(Mk, r0, r1, k);
        float p = Mk[k];
        pp *= p;
        float ip = 1.0f / p;
        bool own0 = (k < 4) && (q == k);
        bool own1 = (k >= 4) && (q == k - 4);
        float m0 = -(own0 ? -1.0f : r0[k]) * ip;
        float m1 = -(own1 ? -1.0f : r1[k]) * ip;
#pragma unroll
        for (int c = 0; c < 8; ++c) {
            float b0 = own0 ? 0.0f : r0[c];
            float b1 = own1 ? 0.0f : r1[c];
            r0[c] = fmaf(m0, Mk[c], b0);
            r1[c] = fmaf(m1, Mk[c], b1);
        }
        r0[k] = m0;
        r1[k] = m1;
    }
    return pp;
}

__global__ __launch_bounds__(256) void pairkl_kernel(
    const float* __restrict__ omega, const float* __restrict__ links,
    const float* __restrict__ mu, const float* __restrict__ sigma,
    float* __restrict__ out) {
    __shared__ __align__(16) float sh_om[GP][NN][STR];  // omega -> y_j (B-wave)
    __shared__ __align__(16) float sh_sg[GP][NN][STR];  // sigma (persists)
    __shared__ __align__(16) float sh_wv[GP][NN][STR];  // V -> x_i (A-wave)
    __shared__ __align__(16) float sh_mu[GP][NN][8];
    __shared__ float sh_ld1[GP][NN];                    // ld1 (B -> A)
#define sh_x sh_wv
#define sh_y sh_om

    const int bid  = blockIdx.x;
    const int work = (bid & 7) * (NWG / 8) + (bid >> 3);  // XCD-bijective swizzle
    const int g0   = work * GP;
    const int t    = threadIdx.x;

    // ---- Phase 0: float4 staging; V = l0+l1-I into wv ----
    {
        const int gl = t >> 7, s = t & 127;
        const int g  = g0 + gl;
        const float4* om4 = (const float4*)omega;
        const float4* sg4 = (const float4*)sigma;
        const float4* lk4 = (const float4*)links;
#pragma unroll
        for (int k = 0; k < 2; ++k) {
            int fc = s + 128 * k;
            int i = fc >> 4, qq = fc & 15;
            int b4 = (i * GG + g) * 16 + qq;
            float4 o  = om4[b4];
            float4 sv = sg4[b4];
            float4 l0 = lk4[((i * 2 + 0) * GG + g) * 16 + qq];
            float4 l1 = lk4[((i * 2 + 1) * GG + g) * 16 + qq];
            float4 v = make_float4(l0.x + l1.x, l0.y + l1.y, l0.z + l1.z, l0.w + l1.w);
            int e0 = qq * 4;
            if (((e0 + 0) >> 3) == ((e0 + 0) & 7)) v.x -= 1.f;
            if (((e0 + 1) >> 3) == ((e0 + 1) & 7)) v.y -= 1.f;
            if (((e0 + 2) >> 3) == ((e0 + 2) & 7)) v.z -= 1.f;
            if (((e0 + 3) >> 3) == ((e0 + 3) & 7)) v.w -= 1.f;
            *(float4*)&sh_om[gl][i][e0] = o;
            *(float4*)&sh_sg[gl][i][e0] = sv;
            *(float4*)&sh_wv[gl][i][e0] = v;
        }
        if (t < 64) {
            int gl2 = t >> 5, mi = (t >> 1) & 15, h = t & 1;
            const float4* mu4 = (const float4*)mu;
            *(float4*)&sh_mu[gl2][mi][h * 4] = mu4[(mi * GG + g0 + gl2) * 2 + h];
        }
    }
    __syncthreads();

    // wave roles: w0: A(g0), w1: A(g1), w2: B(g0), w3: B(g1)
    const int wid  = t >> 6;
    const int gl   = wid & 1;
    const int isB  = wid >> 1;
    const int lane = t & 63;
    const int item = lane >> 2;
    const int q    = lane & 3;

    float R0[8], R1[8];  // A: Winv rows {q,q+4};  B: siginv rows {q,q+4}
    float mq[8];
    ld_row(mq, &sh_mu[gl][item][0]);

    float ldT = 0.f, ld1B = 0.f, ldoB = 0.f, ccB = 0.f;  // per-wave scalars

    // ---- Phase 1a ----
    if (!isB) {
        // T = omega @ V (rows q,q+4), then Winv = T^{-1}
        float o0[8], o1[8];
        ld_row(o0, &sh_om[gl][item][q * 8]);
        ld_row(o1, &sh_om[gl][item][(q + 4) * 8]);
#pragma unroll
        for (int c = 0; c < 8; ++c) { R0[c] = 0.f; R1[c] = 0.f; }
        const float* vv = &sh_wv[gl][item][0];
#pragma unroll
        for (int b = 0; b < 8; ++b) {
            float vr[8]; ld_row(vr, vv + b * 8);
#pragma unroll
            for (int c = 0; c < 8; ++c) {
                R0[c] = fmaf(o0[b], vr[c], R0[c]);
                R1[c] = fmaf(o1[b], vr[c], R1[c]);
            }
        }
        float ppT = gj4(R0, R1, q);
        ldT = logf(fabsf(ppT));      // same on all lanes
    } else {
        // det(omega); siginv = sigma^{-1}; cc = mu^T siginv mu
        float a0[8], a1[8];
        ld_row(a0, &sh_om[gl][item][q * 8]);
        ld_row(a1, &sh_om[gl][item][(q + 4) * 8]);
        float ppo = gj4(a0, a1, q);  // inverse discarded
        ld_row(R0, &sh_sg[gl][item][q * 8]);
        ld_row(R1, &sh_sg[gl][item][(q + 4) * 8]);
        float pps = gj4(R0, R1, q);
        float cq = dot8(R0, mq) * sel_lo(mq, q) + dot8(R1, mq) * sel_hi(mq, q);
        ccB  = qsum(cq);
        ld1B = logf(fabsf(pps));
        ldoB = logf(fabsf(ppo));
        if (q == 0) sh_ld1[gl][item] = ld1B;
    }
    __syncthreads();

    // ---- Phase 1b: build feature vectors.
    //      x_i = [vec64(Q + u u^T), u, a_i, 1, 0, 0]   (A-wave -> sh_wv)
    //      y_j = [vec64(P), -2w, 1, s_j, 0, 0]         (B-wave -> sh_om) ----
    if (!isB) {
        float u_lo = dot8(R0, mq), u_hi = dot8(R1, mq);
        float uf[8];
#pragma unroll
        for (int c = 0; c < 4; ++c) { uf[c] = qb(u_lo, c); uf[c + 4] = qb(u_hi, c); }
        // Z = Winv * sigma
        float Z0[8], Z1[8];
#pragma unroll
        for (int c = 0; c < 8; ++c) { Z0[c] = 0.f; Z1[c] = 0.f; }
        const float* sg = &sh_sg[gl][item][0];
#pragma unroll
        for (int b = 0; b < 8; ++b) {
            float sr[8]; ld_row(sr, sg + b * 8);
#pragma unroll
            for (int c = 0; c < 8; ++c) {
                Z0[c] = fmaf(R0[b], sr[c], Z0[c]);
                Z1[c] = fmaf(R1[b], sr[c], Z1[c]);
            }
        }
        // Q = Z Winv^T ; X = Q + u u^T
        float X0[8], X1[8];
#pragma unroll
        for (int c = 0; c < 8; ++c) {
            float Wc[8]; bcast_row(Wc, R0, R1, c);
            X0[c] = fmaf(u_lo, uf[c], dot8(Z0, Wc));
            X1[c] = fmaf(u_hi, uf[c], dot8(Z1, Wc));
        }
        st_row(&sh_x[gl][item][q * 8], X0);
        st_row(&sh_x[gl][item][(q + 4) * 8], X1);
        if (q == 0) {
            float ld1 = sh_ld1[gl][item];
            float a_i = 2.f * ldT - ld1;
            *(float4*)&sh_x[gl][item][64] = make_float4(uf[0], uf[1], uf[2], uf[3]);
            *(float4*)&sh_x[gl][item][68] = make_float4(uf[4], uf[5], uf[6], uf[7]);
            *(float4*)&sh_x[gl][item][72] = make_float4(a_i, 1.f, 0.f, 0.f);
        }
    } else {
        // S = siginv omega ; P = omega^T S ; w = S^T mu
        float S0[8], S1[8], oq[8], oq4[8];
#pragma unroll
        for (int c = 0; c < 8; ++c) { S0[c] = 0.f; S1[c] = 0.f; }
        const float* om = &sh_om[gl][item][0];
#pragma unroll
        for (int b = 0; b < 8; ++b) {
            float orow[8]; ld_row(orow, om + b * 8);
#pragma unroll
            for (int c = 0; c < 8; ++c) {
                S0[c] = fmaf(R0[b], orow[c], S0[c]);
                S1[c] = fmaf(R1[b], orow[c], S1[c]);
            }
            oq[b]  = sel_lo(orow, q);
            oq4[b] = sel_hi(orow, q);
        }
        float P0[8], P1[8];
#pragma unroll
        for (int c = 0; c < 8; ++c) { P0[c] = 0.f; P1[c] = 0.f; }
#pragma unroll
        for (int a = 0; a < 8; ++a) {
            float Sa[8]; bcast_row(Sa, S0, S1, a);
#pragma unroll
            for (int c = 0; c < 8; ++c) {
                P0[c] = fmaf(oq[a],  Sa[c], P0[c]);
                P1[c] = fmaf(oq4[a], Sa[c], P1[c]);
            }
        }
        float wp[8];
        {
            float mlo = sel_lo(mq, q), mhi = sel_hi(mq, q);
#pragma unroll
            for (int c = 0; c < 8; ++c)
                wp[c] = qsum(fmaf(mlo, S0[c], mhi * S1[c]));
        }
        st_row(&sh_y[gl][item][q * 8], P0);
        st_row(&sh_y[gl][item][(q + 4) * 8], P1);
        if (q == 0) {
            float s_j = ld1B - 2.f * ldoB + ccB - 8.0f;
            *(float4*)&sh_y[gl][item][64] =
                make_float4(-2.f * wp[0], -2.f * wp[1], -2.f * wp[2], -2.f * wp[3]);
            *(float4*)&sh_y[gl][item][68] =
                make_float4(-2.f * wp[4], -2.f * wp[5], -2.f * wp[6], -2.f * wp[7]);
            *(float4*)&sh_y[gl][item][72] = make_float4(1.f, s_j, 0.f, 0.f);
        }
    }
    __syncthreads();

    // ---- Phase 2: E[i,j] = 0.5 * dot76(x_i, y_j); 2i x 2j per thread ----
    if (t < 128) {
        const int gl2 = t >> 6, r = t & 63;
        const int i0 = r >> 3, j0 = r & 7;
        const int i1 = i0 + 8, j1 = j0 + 8;
        const float4* x0 = (const float4*)&sh_x[gl2][i0][0];
        const float4* x1 = (const float4*)&sh_x[gl2][i1][0];
        const float4* y0 = (const float4*)&sh_y[gl2][j0][0];
        const float4* y1 = (const float4*)&sh_y[gl2][j1][0];
        float d00 = 0.f, d01 = 0.f, d10 = 0.f, d11 = 0.f;
#pragma unroll
        for (int k = 0; k < STR / 4; ++k) {
            float4 a0 = x0[k], a1 = x1[k], b0 = y0[k], b1 = y1[k];
            d00 = fmaf(a0.x, b0.x, d00); d00 = fmaf(a0.y, b0.y, d00);
            d00 = fmaf(a0.z, b0.z, d00); d00 = fmaf(a0.w, b0.w, d00);
            d01 = fmaf(a0.x, b1.x, d01); d01 = fmaf(a0.y, b1.y, d01);
            d01 = fmaf(a0.z, b1.z, d01); d01 = fmaf(a0.w, b1.w, d01);
            d10 = fmaf(a1.x, b0.x, d10); d10 = fmaf(a1.y, b0.y, d10);
            d10 = fmaf(a1.z, b0.z, d10); d10 = fmaf(a1.w, b0.w, d10);
            d11 = fmaf(a1.x, b1.x, d11); d11 = fmaf(a1.y, b1.y, d11);
            d11 = fmaf(a1.z, b1.z, d11); d11 = fmaf(a1.w, b1.w, d11);
        }
        const int g = g0 + gl2;
        const bool dg = (i0 == j0);
        out[(i0 * NN + j0) * GG + g] = dg ? 0.f : 0.5f * d00;
        out[(i0 * NN + j1) * GG + g] = 0.5f * d01;
        out[(i1 * NN + j0) * GG + g] = 0.5f * d10;
        out[(i1 * NN + j1) * GG + g] = dg ? 0.f : 0.5f * d11;
    }
}

extern "C" void kernel_launch(void* const* d_in, const int* in_sizes, int n_in,
                              void* d_out, int out_size, void* d_ws, size_t ws_size,
                              hipStream_t stream) {
    const float* omega = (const float*)d_in[0];
    const float* links = (const float*)d_in[1];
    const float* mu    = (const float*)d_in[2];
    const float* sigma = (const float*)d_in[3];
    float* out = (float*)d_out;
    hipLaunchKernelGGL(pairkl_kernel, dim3(NWG), dim3(256), 0, stream,
                       omega, links, mu, sigma, out);
}

// Round 8
// 26.958 us; speedup vs baseline: 2.9632x; 1.0953x over previous
//
#include <hip/hip_runtime.h>
#include <math.h>

#define NN 16
#define GG 4096
#define GP 2
#define STR 76            // 76*4=304 B row stride: bases mod 128 B cycle over 8 slots -> conflict-free
#define NWG (GG / GP)     // 2048 blocks

// ---- DPP helpers (quad_perm = VALU cross-lane, no DS pipe) ----
template <int CTRL>
__device__ __forceinline__ float dppf(float x) {
    return __builtin_bit_cast(float, __builtin_amdgcn_mov_dpp(
        __builtin_bit_cast(int, x), CTRL, 0xF, 0xF, true));
}
__device__ __forceinline__ float qb(float x, int L) {
    switch (L) {
        case 0:  return dppf<0x00>(x);
        case 1:  return dppf<0x55>(x);
        case 2:  return dppf<0xAA>(x);
        default: return dppf<0xFF>(x);
    }
}
__device__ __forceinline__ float qsum(float x) {
    x += dppf<0xB1>(x);  // perm[1,0,3,2]
    x += dppf<0x4E>(x);  // perm[2,3,0,1]
    return x;
}
__device__ __forceinline__ void bcast_row(float out[8], const float r0[8],
                                          const float r1[8], int k) {
#pragma unroll
    for (int c = 0; c < 8; ++c) {
        float s = (k < 4) ? r0[c] : r1[c];
        out[c] = qb(s, k & 3);
    }
}
__device__ __forceinline__ float sel_lo(const float r[8], int q) {
    return (q == 0) ? r[0] : (q == 1) ? r[1] : (q == 2) ? r[2] : r[3];
}
__device__ __forceinline__ float sel_hi(const float r[8], int q) {
    return (q == 0) ? r[4] : (q == 1) ? r[5] : (q == 2) ? r[6] : r[7];
}
__device__ __forceinline__ void ld_row(float r[8], const float* p) {
    float4 x = *(const float4*)p, y = *(const float4*)(p + 4);
    r[0] = x.x; r[1] = x.y; r[2] = x.z; r[3] = x.w;
    r[4] = y.x; r[5] = y.y; r[6] = y.z; r[7] = y.w;
}
__device__ __forceinline__ void st_row(float* p, const float r[8]) {
    *(float4*)p       = make_float4(r[0], r[1], r[2], r[3]);
    *(float4*)(p + 4) = make_float4(r[4], r[5], r[6], r[7]);
}
__device__ __forceinline__ float dot8(const float a[8], const float b[8]) {
    float s = a[0] * b[0];
    s = fmaf(a[1], b[1], s); s = fmaf(a[2], b[2], s);
    s = fmaf(a[3], b[3], s); s = fmaf(a[4], b[4], s);
    s = fmaf(a[5], b[5], s); s = fmaf(a[6], b[6], s);
    s = fmaf(a[7], b[7], s);
    return s;
}

// 4-lane cooperative Gauss-Jordan: lane q holds rows q (r0) and q+4 (r1).
// On return rows hold M^{-1}. Returns pivot product (det), same on all lanes.
// No pivoting (matrices are I+eps or SPD).
__device__ __forceinline__ float gj4(float r0[8], float r1[8], int q) {
    float pp = 1.0f;
#pragma unroll
    for (int k = 0; k < 8; ++k) {
        float Mk[8];
        bcast_row(Mk, r0, r1, k);
        float p = Mk[k];
        pp *= p;
        float ip = 1.0f / p;
        bool own0 = (k < 4) && (q == k);
        bool own1 = (k >= 4) && (q == k - 4);
        float m0 = -(own0 ? -1.0f : r0[k]) * ip;
        float m1 = -(own1 ? -1.0f : r1[k]) * ip;
#pragma unroll
        for (int c = 0; c < 8; ++c) {
            float b0 = own0 ? 0.0f : r0[c];
            float b1 = own1 ? 0.0f : r1[c];
            r0[c] = fmaf(m0, Mk[c], b0);
            r1[c] = fmaf(m1, Mk[c], b1);
        }
        r0[k] = m0;
        r1[k] = m1;
    }
    return pp;
}

__global__ __launch_bounds__(256) void pairkl_kernel(
    const float* __restrict__ omega, const float* __restrict__ links,
    const float* __restrict__ mu, const float* __restrict__ sigma,
    float* __restrict__ out) {
    // Only the feature vectors live in LDS. x by A-waves (plus x[74] by B),
    // y by B-waves. One barrier total.
    __shared__ __align__(16) float sh_x[GP][NN][STR];
    __shared__ __align__(16) float sh_y[GP][NN][STR];

    const int bid  = blockIdx.x;
    const int work = (bid & 7) * (NWG / 8) + (bid >> 3);  // XCD-bijective swizzle
    const int g0   = work * GP;
    const int t    = threadIdx.x;
    const int wid  = t >> 6;
    const int gl   = wid & 1;
    const int isB  = wid >> 1;  // w0:A(g0) w1:A(g1) w2:B(g0) w3:B(g1)
    const int lane = t & 63;
    const int item = lane >> 2;
    const int q    = lane & 3;
    const int g    = g0 + gl;
    const int mb   = (item * GG + g) * 64;  // base float idx of this 8x8 matrix

    if (!isB) {
        // ---------- A-wave: x_i = [vec64(Q+uu^T), u, 2ldT, 1, (-ld1 by B), 0]
        float v0[8], v1[8], o0[8], o1[8], s0[8], s1[8], mq[8];
        {
            const float* l0p = links + ((item * 2 + 0) * GG + g) * 64;
            const float* l1p = links + ((item * 2 + 1) * GG + g) * 64;
            float la[8], lb[8];
            ld_row(la, l0p + q * 8);
            ld_row(lb, l1p + q * 8);
#pragma unroll
            for (int c = 0; c < 8; ++c)
                v0[c] = la[c] + lb[c] - ((c == q) ? 1.f : 0.f);
            ld_row(la, l0p + (q + 4) * 8);
            ld_row(lb, l1p + (q + 4) * 8);
#pragma unroll
            for (int c = 0; c < 8; ++c)
                v1[c] = la[c] + lb[c] - ((c == q + 4) ? 1.f : 0.f);
        }
        ld_row(o0, omega + mb + q * 8);
        ld_row(o1, omega + mb + (q + 4) * 8);
        ld_row(s0, sigma + mb + q * 8);
        ld_row(s1, sigma + mb + (q + 4) * 8);
        ld_row(mq, mu + (item * GG + g) * 8);
        // T = omega @ V   (rows q, q+4)
        float R0[8], R1[8];
#pragma unroll
        for (int c = 0; c < 8; ++c) { R0[c] = 0.f; R1[c] = 0.f; }
#pragma unroll
        for (int b = 0; b < 8; ++b) {
            float Vb[8]; bcast_row(Vb, v0, v1, b);
#pragma unroll
            for (int c = 0; c < 8; ++c) {
                R0[c] = fmaf(o0[b], Vb[c], R0[c]);
                R1[c] = fmaf(o1[b], Vb[c], R1[c]);
            }
        }
        float ldT = logf(fabsf(gj4(R0, R1, q)));  // R = Winv
        // Z = Winv @ sigma
        float Z0[8], Z1[8];
#pragma unroll
        for (int c = 0; c < 8; ++c) { Z0[c] = 0.f; Z1[c] = 0.f; }
#pragma unroll
        for (int b = 0; b < 8; ++b) {
            float Sb[8]; bcast_row(Sb, s0, s1, b);
#pragma unroll
            for (int c = 0; c < 8; ++c) {
                Z0[c] = fmaf(R0[b], Sb[c], Z0[c]);
                Z1[c] = fmaf(R1[b], Sb[c], Z1[c]);
            }
        }
        float u_lo = dot8(R0, mq), u_hi = dot8(R1, mq);
        float uf[8];
#pragma unroll
        for (int c = 0; c < 4; ++c) { uf[c] = qb(u_lo, c); uf[c + 4] = qb(u_hi, c); }
        // X = Z Winv^T + u u^T
        float X0[8], X1[8];
#pragma unroll
        for (int c = 0; c < 8; ++c) {
            float Wc[8]; bcast_row(Wc, R0, R1, c);
            X0[c] = fmaf(u_lo, uf[c], dot8(Z0, Wc));
            X1[c] = fmaf(u_hi, uf[c], dot8(Z1, Wc));
        }
        st_row(&sh_x[gl][item][q * 8], X0);
        st_row(&sh_x[gl][item][(q + 4) * 8], X1);
        if (q == 0) {
            *(float4*)&sh_x[gl][item][64] = make_float4(uf[0], uf[1], uf[2], uf[3]);
            *(float4*)&sh_x[gl][item][68] = make_float4(uf[4], uf[5], uf[6], uf[7]);
            *(float2*)&sh_x[gl][item][72] = make_float2(2.f * ldT, 1.f);
        }
    } else {
        // ---------- B-wave: y_j = [vec64(P), -2w, 1, s_j, 1, 0]; x_i[74] = -ld1
        float o0[8], o1[8], s0[8], s1[8], mq[8];
        ld_row(o0, omega + mb + q * 8);
        ld_row(o1, omega + mb + (q + 4) * 8);
        ld_row(s0, sigma + mb + q * 8);
        ld_row(s1, sigma + mb + (q + 4) * 8);
        ld_row(mq, mu + (item * GG + g) * 8);
        // siginv (in place) + ld1 + cc
        float ld1 = logf(fabsf(gj4(s0, s1, q)));
        float cc  = qsum(dot8(s0, mq) * sel_lo(mq, q) +
                         dot8(s1, mq) * sel_hi(mq, q));
        if (q == 0) *(float2*)&sh_x[gl][item][74] = make_float2(-ld1, 0.f);
        // t1 = omega^T @ siginv   (rows q, q+4)
        float t10[8], t11[8];
#pragma unroll
        for (int c = 0; c < 8; ++c) { t10[c] = 0.f; t11[c] = 0.f; }
#pragma unroll
        for (int a = 0; a < 8; ++a) {
            float Oa[8]; bcast_row(Oa, o0, o1, a);
            float Sa[8]; bcast_row(Sa, s0, s1, a);
            float oqa = sel_lo(Oa, q), oqa4 = sel_hi(Oa, q);
#pragma unroll
            for (int c = 0; c < 8; ++c) {
                t10[c] = fmaf(oqa,  Sa[c], t10[c]);
                t11[c] = fmaf(oqa4, Sa[c], t11[c]);
            }
        }
        float w_lo = dot8(t10, mq), w_hi = dot8(t11, mq);
        float wf[8];
#pragma unroll
        for (int c = 0; c < 4; ++c) { wf[c] = qb(w_lo, c); wf[c + 4] = qb(w_hi, c); }
        // P = t1 @ omega
        float P0[8], P1[8];
#pragma unroll
        for (int c = 0; c < 8; ++c) { P0[c] = 0.f; P1[c] = 0.f; }
#pragma unroll
        for (int b = 0; b < 8; ++b) {
            float Ob[8]; bcast_row(Ob, o0, o1, b);
#pragma unroll
            for (int c = 0; c < 8; ++c) {
                P0[c] = fmaf(t10[b], Ob[c], P0[c]);
                P1[c] = fmaf(t11[b], Ob[c], P1[c]);
            }
        }
        st_row(&sh_y[gl][item][q * 8], P0);
        st_row(&sh_y[gl][item][(q + 4) * 8], P1);
        // det(omega) last — destroys o rows (no longer needed)
        float ldo = logf(fabsf(gj4(o0, o1, q)));
        if (q == 0) {
            float s_j = ld1 - 2.f * ldo + cc - 8.0f;
            *(float4*)&sh_y[gl][item][64] =
                make_float4(-2.f * wf[0], -2.f * wf[1], -2.f * wf[2], -2.f * wf[3]);
            *(float4*)&sh_y[gl][item][68] =
                make_float4(-2.f * wf[4], -2.f * wf[5], -2.f * wf[6], -2.f * wf[7]);
            *(float4*)&sh_y[gl][item][72] = make_float4(1.f, s_j, 1.f, 0.f);
        }
    }
    __syncthreads();

    // ---- Phase 2: E[i,j] = 0.5 * dot76(x_i, y_j); 2i x 2j per thread ----
    if (t < 128) {
        const int gl2 = t >> 6, r = t & 63;
        const int i0 = r >> 3, j0 = r & 7;
        const int i1 = i0 + 8, j1 = j0 + 8;
        const float4* x0 = (const float4*)&sh_x[gl2][i0][0];
        const float4* x1 = (const float4*)&sh_x[gl2][i1][0];
        const float4* y0 = (const float4*)&sh_y[gl2][j0][0];
        const float4* y1 = (const float4*)&sh_y[gl2][j1][0];
        float d00 = 0.f, d01 = 0.f, d10 = 0.f, d11 = 0.f;
#pragma unroll
        for (int k = 0; k < STR / 4; ++k) {
            float4 a0 = x0[k], a1 = x1[k], b0 = y0[k], b1 = y1[k];
            d00 = fmaf(a0.x, b0.x, d00); d00 = fmaf(a0.y, b0.y, d00);
            d00 = fmaf(a0.z, b0.z, d00); d00 = fmaf(a0.w, b0.w, d00);
            d01 = fmaf(a0.x, b1.x, d01); d01 = fmaf(a0.y, b1.y, d01);
            d01 = fmaf(a0.z, b1.z, d01); d01 = fmaf(a0.w, b1.w, d01);
            d10 = fmaf(a1.x, b0.x, d10); d10 = fmaf(a1.y, b0.y, d10);
            d10 = fmaf(a1.z, b0.z, d10); d10 = fmaf(a1.w, b0.w, d10);
            d11 = fmaf(a1.x, b1.x, d11); d11 = fmaf(a1.y, b1.y, d11);
            d11 = fmaf(a1.z, b1.z, d11); d11 = fmaf(a1.w, b1.w, d11);
        }
        const int gg = g0 + gl2;
        const bool dg = (i0 == j0);
        out[(i0 * NN + j0) * GG + gg] = dg ? 0.f : 0.5f * d00;
        out[(i0 * NN + j1) * GG + gg] = 0.5f * d01;
        out[(i1 * NN + j0) * GG + gg] = 0.5f * d10;
        out[(i1 * NN + j1) * GG + gg] = dg ? 0.f : 0.5f * d11;
    }
}

extern "C" void kernel_launch(void* const* d_in, const int* in_sizes, int n_in,
                              void* d_out, int out_size, void* d_ws, size_t ws_size,
                              hipStream_t stream) {
    const float* omega = (const float*)d_in[0];
    const float* links = (const float*)d_in[1];
    const float* mu    = (const float*)d_in[2];
    const float* sigma = (const float*)d_in[3];
    float* out = (float*)d_out;
    hipLaunchKernelGGL(pairkl_kernel, dim3(NWG), dim3(256), 0, stream,
                       omega, links, mu, sigma, out);
}

// Round 9
// 26.881 us; speedup vs baseline: 2.9716x; 1.0029x over previous
//
#include <hip/hip_runtime.h>
#include <math.h>

#define NN 16
#define GG 4096
#define STR 76            // 76 floats: phase-2 streams hit all 32 banks exactly once
#define NWG GG            // 4096 blocks, 1 wave per block, 1 grid point per wave

// ---- DPP helpers (quad_perm = VALU cross-lane, no DS pipe) ----
template <int CTRL>
__device__ __forceinline__ float dppf(float x) {
    return __builtin_bit_cast(float, __builtin_amdgcn_mov_dpp(
        __builtin_bit_cast(int, x), CTRL, 0xF, 0xF, true));
}
__device__ __forceinline__ float qb(float x, int L) {
    switch (L) {
        case 0:  return dppf<0x00>(x);
        case 1:  return dppf<0x55>(x);
        case 2:  return dppf<0xAA>(x);
        default: return dppf<0xFF>(x);
    }
}
__device__ __forceinline__ float qsum(float x) {
    x += dppf<0xB1>(x);  // perm[1,0,3,2]
    x += dppf<0x4E>(x);  // perm[2,3,0,1]
    return x;
}
__device__ __forceinline__ void bcast_row(float out[8], const float r0[8],
                                          const float r1[8], int k) {
#pragma unroll
    for (int c = 0; c < 8; ++c) {
        float s = (k < 4) ? r0[c] : r1[c];
        out[c] = qb(s, k & 3);
    }
}
__device__ __forceinline__ float sel_lo(const float r[8], int q) {
    return (q == 0) ? r[0] : (q == 1) ? r[1] : (q == 2) ? r[2] : r[3];
}
__device__ __forceinline__ float sel_hi(const float r[8], int q) {
    return (q == 0) ? r[4] : (q == 1) ? r[5] : (q == 2) ? r[6] : r[7];
}
__device__ __forceinline__ void ld_row(float r[8], const float* p) {
    float4 x = *(const float4*)p, y = *(const float4*)(p + 4);
    r[0] = x.x; r[1] = x.y; r[2] = x.z; r[3] = x.w;
    r[4] = y.x; r[5] = y.y; r[6] = y.z; r[7] = y.w;
}
__device__ __forceinline__ void st_row(float* p, const float r[8]) {
    *(float4*)p       = make_float4(r[0], r[1], r[2], r[3]);
    *(float4*)(p + 4) = make_float4(r[4], r[5], r[6], r[7]);
}
__device__ __forceinline__ float dot8(const float a[8], const float b[8]) {
    float s = a[0] * b[0];
    s = fmaf(a[1], b[1], s); s = fmaf(a[2], b[2], s);
    s = fmaf(a[3], b[3], s); s = fmaf(a[4], b[4], s);
    s = fmaf(a[5], b[5], s); s = fmaf(a[6], b[6], s);
    s = fmaf(a[7], b[7], s);
    return s;
}

// 4-lane cooperative Gauss-Jordan: lane q holds rows q (r0) and q+4 (r1).
// On return rows hold M^{-1}. Returns pivot product (det), same on all lanes.
// No pivoting (matrices are I+eps or SPD).
__device__ __forceinline__ float gj4(float r0[8], float r1[8], int q) {
    float pp = 1.0f;
#pragma unroll
    for (int k = 0; k < 8; ++k) {
        float Mk[8];
        bcast_row(Mk, r0, r1, k);
        float p = Mk[k];
        pp *= p;
        float ip = 1.0f / p;
        bool own0 = (k < 4) && (q == k);
        bool own1 = (k >= 4) && (q == k - 4);
        float m0 = -(own0 ? -1.0f : r0[k]) * ip;
        float m1 = -(own1 ? -1.0f : r1[k]) * ip;
#pragma unroll
        for (int c = 0; c < 8; ++c) {
            float b0 = own0 ? 0.0f : r0[c];
            float b1 = own1 ? 0.0f : r1[c];
            r0[c] = fmaf(m0, Mk[c], b0);
            r1[c] = fmaf(m1, Mk[c], b1);
        }
        r0[k] = m0;
        r1[k] = m1;
    }
    return pp;
}

__global__ __launch_bounds__(64) void pairkl_kernel(
    const float* __restrict__ omega, const float* __restrict__ links,
    const float* __restrict__ mu, const float* __restrict__ sigma,
    float* __restrict__ out) {
    // Per-wave private feature vectors; no cross-wave sharing, no barriers.
    __shared__ __align__(16) float sh_x[NN][STR];
    __shared__ __align__(16) float sh_y[NN][STR];

    const int bid  = blockIdx.x;
    const int g    = (bid & 7) * (NWG / 8) + (bid >> 3);  // XCD-bijective swizzle
    const int lane = threadIdx.x;
    const int item = lane >> 2;
    const int q    = lane & 3;
    const int mb   = (item * GG + g) * 64;

    // ---- Load everything once (rows q, q+4 of each 8x8) ----
    float o0[8], o1[8], s0[8], s1[8], v0[8], v1[8], mq[8];
    {
        const float* l0p = links + ((item * 2 + 0) * GG + g) * 64;
        const float* l1p = links + ((item * 2 + 1) * GG + g) * 64;
        float la[8], lb[8];
        ld_row(la, l0p + q * 8);
        ld_row(lb, l1p + q * 8);
#pragma unroll
        for (int c = 0; c < 8; ++c) v0[c] = la[c] + lb[c] - ((c == q) ? 1.f : 0.f);
        ld_row(la, l0p + (q + 4) * 8);
        ld_row(lb, l1p + (q + 4) * 8);
#pragma unroll
        for (int c = 0; c < 8; ++c) v1[c] = la[c] + lb[c] - ((c == q + 4) ? 1.f : 0.f);
    }
    ld_row(o0, omega + mb + q * 8);
    ld_row(o1, omega + mb + (q + 4) * 8);
    ld_row(s0, sigma + mb + q * 8);
    ld_row(s1, sigma + mb + (q + 4) * 8);
    ld_row(mq, mu + (item * GG + g) * 8);

    // ---- A-part: x = [vec64(W^-1 sigma W^-T + u u^T), u, a_i, 1, 0, 0] ----
    float ldT, u_lo, u_hi, uf[8];
    {
        // T = omega @ V (rows q, q+4)
        float R0[8], R1[8];
#pragma unroll
        for (int c = 0; c < 8; ++c) { R0[c] = 0.f; R1[c] = 0.f; }
#pragma unroll
        for (int b = 0; b < 8; ++b) {
            float Vb[8]; bcast_row(Vb, v0, v1, b);
#pragma unroll
            for (int c = 0; c < 8; ++c) {
                R0[c] = fmaf(o0[b], Vb[c], R0[c]);
                R1[c] = fmaf(o1[b], Vb[c], R1[c]);
            }
        }
        ldT = logf(fabsf(gj4(R0, R1, q)));  // R = Winv
        // Z = Winv @ sigma (original sigma still intact)
        float Z0[8], Z1[8];
#pragma unroll
        for (int c = 0; c < 8; ++c) { Z0[c] = 0.f; Z1[c] = 0.f; }
#pragma unroll
        for (int b = 0; b < 8; ++b) {
            float Sb[8]; bcast_row(Sb, s0, s1, b);
#pragma unroll
            for (int c = 0; c < 8; ++c) {
                Z0[c] = fmaf(R0[b], Sb[c], Z0[c]);
                Z1[c] = fmaf(R1[b], Sb[c], Z1[c]);
            }
        }
        u_lo = dot8(R0, mq);
        u_hi = dot8(R1, mq);
#pragma unroll
        for (int c = 0; c < 4; ++c) { uf[c] = qb(u_lo, c); uf[c + 4] = qb(u_hi, c); }
        // X = Z Winv^T + u u^T  -> reuse v regs (V dead after T)
#pragma unroll
        for (int c = 0; c < 8; ++c) {
            float Wc[8]; bcast_row(Wc, R0, R1, c);
            v0[c] = fmaf(u_lo, uf[c], dot8(Z0, Wc));
            v1[c] = fmaf(u_hi, uf[c], dot8(Z1, Wc));
        }
        st_row(&sh_x[item][q * 8], v0);
        st_row(&sh_x[item][(q + 4) * 8], v1);
    }

    // ---- B-part: y = [vec64(om^T siginv om), -2w, 1, s_j, 0, 0] ----
    float ld1, cc, wf[8];
    {
        ld1 = logf(fabsf(gj4(s0, s1, q)));  // s rows now = siginv
        cc  = qsum(dot8(s0, mq) * sel_lo(mq, q) + dot8(s1, mq) * sel_hi(mq, q));
        // t1 = omega^T @ siginv (rows q, q+4)
        float t10[8], t11[8];
#pragma unroll
        for (int c = 0; c < 8; ++c) { t10[c] = 0.f; t11[c] = 0.f; }
#pragma unroll
        for (int a = 0; a < 8; ++a) {
            float Oa[8]; bcast_row(Oa, o0, o1, a);
            float Sa[8]; bcast_row(Sa, s0, s1, a);
            float oqa = sel_lo(Oa, q), oqa4 = sel_hi(Oa, q);
#pragma unroll
            for (int c = 0; c < 8; ++c) {
                t10[c] = fmaf(oqa,  Sa[c], t10[c]);
                t11[c] = fmaf(oqa4, Sa[c], t11[c]);
            }
        }
        float w_lo = dot8(t10, mq), w_hi = dot8(t11, mq);
#pragma unroll
        for (int c = 0; c < 4; ++c) { wf[c] = qb(w_lo, c); wf[c + 4] = qb(w_hi, c); }
        // P = t1 @ omega  -> reuse s regs (siginv dead after t1)
#pragma unroll
        for (int c = 0; c < 8; ++c) { s0[c] = 0.f; s1[c] = 0.f; }
#pragma unroll
        for (int b = 0; b < 8; ++b) {
            float Ob[8]; bcast_row(Ob, o0, o1, b);
#pragma unroll
            for (int c = 0; c < 8; ++c) {
                s0[c] = fmaf(t10[b], Ob[c], s0[c]);
                s1[c] = fmaf(t11[b], Ob[c], s1[c]);
            }
        }
        st_row(&sh_y[item][q * 8], s0);
        st_row(&sh_y[item][(q + 4) * 8], s1);
    }
    // det(omega) last (destroys o rows)
    float ldo = logf(fabsf(gj4(o0, o1, q)));

    if (q == 0) {
        float a_i = 2.f * ldT - ld1;
        float s_j = ld1 - 2.f * ldo + cc - 8.0f;
        *(float4*)&sh_x[item][64] = make_float4(uf[0], uf[1], uf[2], uf[3]);
        *(float4*)&sh_x[item][68] = make_float4(uf[4], uf[5], uf[6], uf[7]);
        *(float4*)&sh_x[item][72] = make_float4(a_i, 1.f, 0.f, 0.f);
        *(float4*)&sh_y[item][64] =
            make_float4(-2.f * wf[0], -2.f * wf[1], -2.f * wf[2], -2.f * wf[3]);
        *(float4*)&sh_y[item][68] =
            make_float4(-2.f * wf[4], -2.f * wf[5], -2.f * wf[6], -2.f * wf[7]);
        *(float4*)&sh_y[item][72] = make_float4(1.f, s_j, 0.f, 0.f);
    }
    // no __syncthreads: single-wave workgroup; DS ops complete in program
    // order and the compiler inserts lgkmcnt waits for the RAW dependency.
    asm volatile("" ::: "memory");

    // ---- Phase 2: E[i,j] = 0.5 * dot76(x_i, y_j); 2i x 2j per lane ----
    {
        const int i0 = lane >> 3, j0 = lane & 7;
        const int i1 = i0 + 8, j1 = j0 + 8;
        const float4* x0 = (const float4*)&sh_x[i0][0];
        const float4* x1 = (const float4*)&sh_x[i1][0];
        const float4* y0 = (const float4*)&sh_y[j0][0];
        const float4* y1 = (const float4*)&sh_y[j1][0];
        float d00 = 0.f, d01 = 0.f, d10 = 0.f, d11 = 0.f;
#pragma unroll
        for (int k = 0; k < STR / 4; ++k) {
            float4 a0 = x0[k], a1 = x1[k], b0 = y0[k], b1 = y1[k];
            d00 = fmaf(a0.x, b0.x, d00); d00 = fmaf(a0.y, b0.y, d00);
            d00 = fmaf(a0.z, b0.z, d00); d00 = fmaf(a0.w, b0.w, d00);
            d01 = fmaf(a0.x, b1.x, d01); d01 = fmaf(a0.y, b1.y, d01);
            d01 = fmaf(a0.z, b1.z, d01); d01 = fmaf(a0.w, b1.w, d01);
            d10 = fmaf(a1.x, b0.x, d10); d10 = fmaf(a1.y, b0.y, d10);
            d10 = fmaf(a1.z, b0.z, d10); d10 = fmaf(a1.w, b0.w, d10);
            d11 = fmaf(a1.x, b1.x, d11); d11 = fmaf(a1.y, b1.y, d11);
            d11 = fmaf(a1.z, b1.z, d11); d11 = fmaf(a1.w, b1.w, d11);
        }
        const bool dg = (i0 == j0);
        out[(i0 * NN + j0) * GG + g] = dg ? 0.f : 0.5f * d00;
        out[(i0 * NN + j1) * GG + g] = 0.5f * d01;
        out[(i1 * NN + j0) * GG + g] = 0.5f * d10;
        out[(i1 * NN + j1) * GG + g] = dg ? 0.f : 0.5f * d11;
    }
}

extern "C" void kernel_launch(void* const* d_in, const int* in_sizes, int n_in,
                              void* d_out, int out_size, void* d_ws, size_t ws_size,
                              hipStream_t stream) {
    const float* omega = (const float*)d_in[0];
    const float* links = (const float*)d_in[1];
    const float* mu    = (const float*)d_in[2];
    const float* sigma = (const float*)d_in[3];
    float* out = (float*)d_out;
    hipLaunchKernelGGL(pairkl_kernel, dim3(NWG), dim3(64), 0, stream,
                       omega, links, mu, sigma, out);
}